// Round 2
// baseline (157.889 us; speedup 1.0000x reference)
//
#include <hip/hip_runtime.h>
#include <stdint.h>

#define B_ROWS 16384
#define C_COLS 1000
#define D_DIM  2048
#define TM 128
#define TN 128
#define BK 64

typedef __bf16 bf16x8 __attribute__((ext_vector_type(8)));
typedef float  f32x4  __attribute__((ext_vector_type(4)));
typedef unsigned short u16;

__device__ __forceinline__ u16 f2bf(float f) {
  union { float f; uint32_t u; } v; v.f = f;
  return (u16)((v.u + 0x7FFFu + ((v.u >> 16) & 1u)) >> 16);
}

// ---------------------------------------------------------------------------
// Kernel 1: cast W -> bf16 (XOR-swizzled per 64-elem chunk) + row norms (f32)
// ---------------------------------------------------------------------------
__global__ __launch_bounds__(256)
void prep_w(const float* __restrict__ W, u16* __restrict__ Wb,
            float* __restrict__ norms) {
  const int r = blockIdx.x;          // W row, 0..999
  const int t = threadIdx.x;         // 256 threads, 8 elems each (2048/256)
  const float* row = W + (size_t)r * D_DIM;
  const int c = t * 8;
  float4 v0 = *reinterpret_cast<const float4*>(row + c);
  float4 v1 = *reinterpret_cast<const float4*>(row + c + 4);
  float ss = v0.x*v0.x + v0.y*v0.y + v0.z*v0.z + v0.w*v0.w
           + v1.x*v1.x + v1.y*v1.y + v1.z*v1.z + v1.w*v1.w;
  uint32_t p0 = (uint32_t)f2bf(v0.x) | ((uint32_t)f2bf(v0.y) << 16);
  uint32_t p1 = (uint32_t)f2bf(v0.z) | ((uint32_t)f2bf(v0.w) << 16);
  uint32_t p2 = (uint32_t)f2bf(v1.x) | ((uint32_t)f2bf(v1.y) << 16);
  uint32_t p3 = (uint32_t)f2bf(v1.z) | ((uint32_t)f2bf(v1.w) << 16);
  const int mask = (r & 7) << 3;     // swizzle within each 64-elem (128B) chunk
  uint4 val; val.x = p0; val.y = p1; val.z = p2; val.w = p3;
  *reinterpret_cast<uint4*>(Wb + (size_t)r * D_DIM + (c ^ mask)) = val;
  // block reduction for ||W_r||
  #pragma unroll
  for (int m = 32; m; m >>= 1) ss += __shfl_xor(ss, m);
  __shared__ float wss[4];
  if ((t & 63) == 0) wss[t >> 6] = ss;
  __syncthreads();
  if (t == 0) norms[r] = sqrtf(wss[0] + wss[1] + wss[2] + wss[3]);
}

// ---------------------------------------------------------------------------
// Kernel 2: logits = x * W^T + b   (bf16 MFMA, f32 out)
// 128x128 tile, BK=64, 4 waves, double-buffered LDS, counted waits + raw
// barriers; A reg-staged (f32 -> cvt_pk bf16 -> ds_write_b128), B gload_lds.
// ---------------------------------------------------------------------------
__global__ __launch_bounds__(256, 2)
void gemm_bf16(const float* __restrict__ x, const u16* __restrict__ Wb,
               const float* __restrict__ bias, float* __restrict__ out) {
  __shared__ u16 lds[2][(TM + TN) * BK];   // 64 KiB: [buf][A 8192 | B 8192]

  // XCD-aware bijective swizzle (1024 blocks, %8==0)
  const int bid = blockIdx.x;
  const int cpx = gridDim.x >> 3;
  const int swz = (bid & 7) * cpx + (bid >> 3);
  const int tn = swz & 7;            // 8 n-tiles (1000 -> padded 1024)
  const int tm = swz >> 3;           // 128 m-tiles
  const int m0 = tm * TM;
  const int n0 = tn * TN;

  const int t = threadIdx.x;
  const int w = t >> 6;
  const int l = t & 63;
  const int wr = w >> 1, wc = w & 1;

  f32x4 acc[4][4];
  #pragma unroll
  for (int i = 0; i < 4; ++i)
    #pragma unroll
    for (int j = 0; j < 4; ++j)
      acc[i][j] = (f32x4){0.f, 0.f, 0.f, 0.f};

  // A prefetch mapping: thread -> rows (t>>3)+p*32, cols (t&7)*8 .. +7
  const int pr = t >> 3;
  const int pc = (t & 7) * 8;
  const float* abase = x + (size_t)(m0 + pr) * D_DIM + pc;
  float4 af4[8];

#define ISSUE_A(K0) { _Pragma("unroll") for (int p = 0; p < 4; ++p) { \
    const float* s_ = abase + (size_t)(p * 32) * D_DIM + (K0); \
    af4[2*p]   = *reinterpret_cast<const float4*>(s_); \
    af4[2*p+1] = *reinterpret_cast<const float4*>(s_ + 4); } }

#define WRITE_A(BUF) { _Pragma("unroll") for (int p = 0; p < 4; ++p) { \
    int r_ = pr + p * 32; \
    bf16x8 h_; \
    h_[0]=(__bf16)af4[2*p].x;   h_[1]=(__bf16)af4[2*p].y; \
    h_[2]=(__bf16)af4[2*p].z;   h_[3]=(__bf16)af4[2*p].w; \
    h_[4]=(__bf16)af4[2*p+1].x; h_[5]=(__bf16)af4[2*p+1].y; \
    h_[6]=(__bf16)af4[2*p+1].z; h_[7]=(__bf16)af4[2*p+1].w; \
    *reinterpret_cast<bf16x8*>(&lds[BUF][r_ * BK + (pc ^ ((r_ & 7) << 3))]) = h_; } }

#define ISSUE_B(BUF, K0) { _Pragma("unroll") for (int i = 0; i < 4; ++i) { \
    int ci_ = w * 4 + i; \
    int br_ = ci_ * 8 + (l >> 3); \
    int wrow_ = n0 + br_; if (wrow_ >= C_COLS) wrow_ = C_COLS - 1; \
    const char* src_ = (const char*)Wb + (size_t)wrow_ * (D_DIM * 2) \
                       + (K0) * 2 + (l & 7) * 16; \
    void* dst_ = (void*)((char*)(&lds[BUF][TM * BK]) + ci_ * 1024); \
    __builtin_amdgcn_global_load_lds( \
        (const __attribute__((address_space(1))) void*)src_, \
        (__attribute__((address_space(3))) void*)dst_, 16, 0, 0); } }

#define COMPUTE(BUF) { \
    const u16* LA_ = &lds[BUF][0]; \
    const u16* LB_ = &lds[BUF][TM * BK]; \
    _Pragma("unroll") for (int kk = 0; kk < BK; kk += 32) { \
      const int kg_ = kk + ((l >> 4) << 3); \
      bf16x8 afr[4], bfr[4]; \
      _Pragma("unroll") for (int mi = 0; mi < 4; ++mi) { \
        int row_ = wr * 64 + mi * 16 + (l & 15); \
        afr[mi] = *reinterpret_cast<const bf16x8*>( \
            &LA_[row_ * BK + (kg_ ^ ((row_ & 7) << 3))]); } \
      _Pragma("unroll") for (int ni = 0; ni < 4; ++ni) { \
        int row_ = wc * 64 + ni * 16 + (l & 15); \
        bfr[ni] = *reinterpret_cast<const bf16x8*>( \
            &LB_[row_ * BK + (kg_ ^ ((row_ & 7) << 3))]); } \
      _Pragma("unroll") for (int mi = 0; mi < 4; ++mi) \
        _Pragma("unroll") for (int ni = 0; ni < 4; ++ni) \
          acc[mi][ni] = __builtin_amdgcn_mfma_f32_16x16x32_bf16( \
              afr[mi], bfr[ni], acc[mi][ni], 0, 0, 0); } }

  // prologue: stage tile 0 into buf 0
  ISSUE_A(0); ISSUE_B(0, 0);
  WRITE_A(0);  // compiler inserts counted vmcnt for af4 deps
  asm volatile("s_waitcnt vmcnt(0) lgkmcnt(0)\ns_barrier" ::: "memory");

  for (int it = 0; it < D_DIM / BK; ++it) {
    const int cur = it & 1, pre = cur ^ 1;
    if (it < D_DIM / BK - 1) {
      ISSUE_A((it + 1) * BK);        // f32 -> regs, in flight across compute
      ISSUE_B(pre, (it + 1) * BK);   // gload_lds -> other buffer, in flight
    }
    COMPUTE(cur);
    if (it < D_DIM / BK - 1) {
      WRITE_A(pre);                  // cvt + ds_write (waits only on af4)
      asm volatile("s_waitcnt vmcnt(0) lgkmcnt(0)\ns_barrier" ::: "memory");
    }
  }

  // ---- epilogue: + bias, bounds-checked store (C/D: col=lane&15, row=(lane>>4)*4+j)
  #pragma unroll
  for (int ni = 0; ni < 4; ++ni) {
    int col = n0 + wc * 64 + ni * 16 + (l & 15);
    if (col < C_COLS) {
      float bv = bias[col];
      #pragma unroll
      for (int mi = 0; mi < 4; ++mi) {
        int row0 = m0 + wr * 64 + mi * 16 + ((l >> 4) << 2);
        #pragma unroll
        for (int j = 0; j < 4; ++j)
          out[(size_t)(row0 + j) * C_COLS + col] = acc[mi][ni][j] + bv;
      }
    }
  }
#undef ISSUE_A
#undef WRITE_A
#undef ISSUE_B
#undef COMPUTE
}

// ---------------------------------------------------------------------------
// Kernel 3: per-row selectors -> selection_score  (1 wave per row)
// ---------------------------------------------------------------------------
__global__ __launch_bounds__(256)
void selector(const float* __restrict__ logits, const float* __restrict__ norms,
              const float* __restrict__ selw, const float* __restrict__ selt,
              const float* __restrict__ ethr, float* __restrict__ out) {
  __shared__ float nrm[C_COLS];
  const int t = threadIdx.x;
  for (int i = t; i < C_COLS; i += 256) nrm[i] = norms[i];
  __syncthreads();

  const int w = t >> 6, l = t & 63;
  const int row = blockIdx.x * 4 + w;
  const float* lp = logits + (size_t)row * C_COLS;

  float lg[16];
  float t1 = -3.4e38f, t2 = -3.4e38f, n1 = -3.4e38f, n2 = -3.4e38f;
  #pragma unroll
  for (int i = 0; i < 16; ++i) {
    int idx = l + i * 64;
    float v = (idx < C_COLS) ? lp[idx] : -3.4e38f;
    lg[i] = v;
    if (v > t1) { t2 = t1; t1 = v; } else if (v > t2) t2 = v;
    float nv = (idx < C_COLS) ? v / (nrm[idx] + 1e-8f) : -3.4e38f;
    if (nv > n1) { n2 = n1; n1 = nv; } else if (nv > n2) n2 = nv;
  }
  // wave-wide top-2 merge (raw + normalized)
  #pragma unroll
  for (int m = 1; m < 64; m <<= 1) {
    float o1 = __shfl_xor(t1, m), o2 = __shfl_xor(t2, m);
    if (o1 > t1) { t2 = fmaxf(t1, o2); t1 = o1; } else t2 = fmaxf(t2, o1);
    float p1 = __shfl_xor(n1, m), p2 = __shfl_xor(n2, m);
    if (p1 > n1) { n2 = fmaxf(n1, p2); n1 = p1; } else n2 = fmaxf(n2, p1);
  }
  const float mx = t1;  // true row max

  float S = 0.f, sq = 0.f;
  float ex[16];
  #pragma unroll
  for (int i = 0; i < 16; ++i) {
    int idx = l + i * 64;
    float e = (idx < C_COLS) ? __expf(lg[i] - mx) : 0.f;
    ex[i] = e; S += e; sq += e * e;
  }
  #pragma unroll
  for (int m = 1; m < 64; m <<= 1) { S += __shfl_xor(S, m); sq += __shfl_xor(sq, m); }

  float ent = 0.f;
  #pragma unroll
  for (int i = 0; i < 16; ++i) {
    int idx = l + i * 64;
    if (idx < C_COLS) {
      float p = ex[i] / S;
      ent += p * __logf(p + 1e-10f);
    }
  }
  #pragma unroll
  for (int m = 1; m < 64; m <<= 1) ent += __shfl_xor(ent, m);

  if (l == 0) {
    float sc0 = 1.f / S;               // SRMax: max prob = exp(0)/S
    float sc1 = 1.f - (S * S) / sq;    // SRDoctor: 1 - 1/sum(p^2)
    float sc2 = ent;                   // SREntropy (neg-entropy)
    float sc3 = n1 - n2;               // RLGeoM
    float sc4 = t1 - t2;               // RLConfM
    float ens = selw[0] * tanhf(sc0 - selt[0])
              + selw[1] * tanhf(sc1 - selt[1])
              + selw[2] * tanhf(sc2 - selt[2])
              + selw[3] * tanhf(sc3 - selt[3])
              + selw[4] * tanhf(sc4 - selt[4]);
    out[row] = tanhf(ens - ethr[0]);
  }
}

// ---------------------------------------------------------------------------
extern "C" void kernel_launch(void* const* d_in, const int* in_sizes, int n_in,
                              void* d_out, int out_size, void* d_ws, size_t ws_size,
                              hipStream_t stream) {
  const float* x    = (const float*)d_in[0];
  const float* W    = (const float*)d_in[1];
  const float* b    = (const float*)d_in[2];
  const float* selw = (const float*)d_in[3];
  const float* selt = (const float*)d_in[4];
  const float* ethr = (const float*)d_in[5];
  float* out = (float*)d_out;

  u16*   Wb    = (u16*)d_ws;                                     // 4,096,000 B
  float* norms = (float*)((char*)d_ws + (size_t)C_COLS * D_DIM * 2);  // +4,000 B

  prep_w<<<C_COLS, 256, 0, stream>>>(W, Wb, norms);
  gemm_bf16<<<(B_ROWS / TM) * 8, 256, 0, stream>>>(x, Wb, b, out);
  selector<<<B_ROWS / 4, 256, 0, stream>>>(out, norms, selw, selt, ethr,
                                           out + (size_t)B_ROWS * C_COLS);
}

// Round 3
// 142.345 us; speedup vs baseline: 1.1092x; 1.1092x over previous
//
#include <hip/hip_runtime.h>
#include <stdint.h>

#define B_ROWS 16384
#define C_COLS 1000
#define D_DIM  2048

typedef __bf16 bf16x8 __attribute__((ext_vector_type(8)));
typedef float  f32x4  __attribute__((ext_vector_type(4)));
typedef unsigned short u16;

__device__ __forceinline__ u16 f2bf(float f) {
  union { float f; uint32_t u; } v; v.f = f;
  return (u16)((v.u + 0x7FFFu + ((v.u >> 16) & 1u)) >> 16);
}

// ---------------------------------------------------------------------------
// prep: blocks 0..999 cast W row -> Wb (swizzled) + norms; blocks 1000..17383
// cast x row (r-1000) -> xb (swizzled). Swizzle: elem c -> c ^ ((row&7)<<3)
// within each 64-elem chunk (matches GEMM ds_read XOR).
// ---------------------------------------------------------------------------
__global__ __launch_bounds__(256)
void prep(const float* __restrict__ W, const float* __restrict__ x,
          u16* __restrict__ Wb, u16* __restrict__ xb, float* __restrict__ norms) {
  const int r = blockIdx.x;
  const int t = threadIdx.x;
  const bool isW = (r < C_COLS);
  const float* src = isW ? (W + (size_t)r * D_DIM)
                         : (x + (size_t)(r - C_COLS) * D_DIM);
  u16* dst = isW ? (Wb + (size_t)r * D_DIM)
                 : (xb + (size_t)(r - C_COLS) * D_DIM);
  const int c = t * 8;
  float4 v0 = *reinterpret_cast<const float4*>(src + c);
  float4 v1 = *reinterpret_cast<const float4*>(src + c + 4);
  uint32_t p0 = (uint32_t)f2bf(v0.x) | ((uint32_t)f2bf(v0.y) << 16);
  uint32_t p1 = (uint32_t)f2bf(v0.z) | ((uint32_t)f2bf(v0.w) << 16);
  uint32_t p2 = (uint32_t)f2bf(v1.x) | ((uint32_t)f2bf(v1.y) << 16);
  uint32_t p3 = (uint32_t)f2bf(v1.z) | ((uint32_t)f2bf(v1.w) << 16);
  const int mask = (r & 7) << 3;   // for x rows: ((r-1000)&7) != (r&7)! fix below
  const int row_id = isW ? r : (r - C_COLS);
  const int m2 = (row_id & 7) << 3;
  (void)mask;
  uint4 val; val.x = p0; val.y = p1; val.z = p2; val.w = p3;
  *reinterpret_cast<uint4*>(dst + (c ^ m2)) = val;
  if (isW) {
    float ss = v0.x*v0.x + v0.y*v0.y + v0.z*v0.z + v0.w*v0.w
             + v1.x*v1.x + v1.y*v1.y + v1.z*v1.z + v1.w*v1.w;
    #pragma unroll
    for (int m = 32; m; m >>= 1) ss += __shfl_xor(ss, m);
    __shared__ float wss[4];
    if ((t & 63) == 0) wss[t >> 6] = ss;
    __syncthreads();
    if (t == 0) norms[r] = sqrtf(wss[0] + wss[1] + wss[2] + wss[3]);
  }
}

// ---------------------------------------------------------------------------
// gemm8: 256x256 tile, BK=64, 8 waves (2M x 4N, interleaved halves), 8-phase
// schedule, counted vmcnt, st-swizzled LDS, gload_lds both operands.
// ---------------------------------------------------------------------------
#define ABASE(B,H) (((B)*2+(H))*8192)
#define BBASE(B,H) (32768 + ((B)*2+(H))*8192)

#define STAGE_A(BUF,H,KT) { _Pragma("unroll") for (int j_=0;j_<2;++j_){ \
    const char* s_ = (const char*)xb + \
      (((size_t)(m0+(H)*128+j_*64+w*8+(l>>3)))*D_DIM + (KT)*64 + (l&7)*8)*2; \
    u16* d_ = lds + ABASE(BUF,H) + (j_*64 + w*8)*64; \
    __builtin_amdgcn_global_load_lds( \
      (const __attribute__((address_space(1))) void*)s_, \
      (__attribute__((address_space(3))) void*)d_, 16, 0, 0); } }

#define STAGE_B(BUF,H,KT) { _Pragma("unroll") for (int j_=0;j_<2;++j_){ \
    int gr_ = n0+(H)*128+j_*64+w*8+(l>>3); if (gr_ >= C_COLS) gr_ = C_COLS-1; \
    const char* s_ = (const char*)Wb + \
      (((size_t)gr_)*D_DIM + (KT)*64 + (l&7)*8)*2; \
    u16* d_ = lds + BBASE(BUF,H) + (j_*64 + w*8)*64; \
    __builtin_amdgcn_global_load_lds( \
      (const __attribute__((address_space(1))) void*)s_, \
      (__attribute__((address_space(3))) void*)d_, 16, 0, 0); } }

#define PHASE(BUF,MH,NH,STG,VMW) { \
  bf16x8 Af[2][4], Bf[2][2]; \
  _Pragma("unroll") for (int ks=0;ks<2;++ks){ \
    _Pragma("unroll") for (int fr=0;fr<4;++fr){ \
      int ra = wr*64 + fr*16 + (l&15); \
      int ca = (ks*32 + ((l>>4)<<3)) ^ ((ra&7)<<3); \
      Af[ks][fr] = *reinterpret_cast<const bf16x8*>(&lds[ABASE(BUF,MH) + ra*64 + ca]); } \
    _Pragma("unroll") for (int fc=0;fc<2;++fc){ \
      int rb = wcn*32 + fc*16 + (l&15); \
      int cb = (ks*32 + ((l>>4)<<3)) ^ ((rb&7)<<3); \
      Bf[ks][fc] = *reinterpret_cast<const bf16x8*>(&lds[BBASE(BUF,NH) + rb*64 + cb]); } } \
  STG; \
  __builtin_amdgcn_s_barrier(); \
  asm volatile("s_waitcnt lgkmcnt(0)" ::: "memory"); \
  __builtin_amdgcn_sched_barrier(0); \
  __builtin_amdgcn_s_setprio(1); \
  _Pragma("unroll") for (int ks=0;ks<2;++ks) \
    _Pragma("unroll") for (int fr=0;fr<4;++fr) \
      _Pragma("unroll") for (int fc=0;fc<2;++fc) \
        acc[MH][fr][NH][fc] = __builtin_amdgcn_mfma_f32_16x16x32_bf16( \
            Af[ks][fr], Bf[ks][fc], acc[MH][fr][NH][fc], 0, 0, 0); \
  __builtin_amdgcn_s_setprio(0); \
  VMW; \
  __builtin_amdgcn_s_barrier(); }

#define VM4 asm volatile("s_waitcnt vmcnt(4)" ::: "memory")
#define VM0 asm volatile("s_waitcnt vmcnt(0)" ::: "memory")
#define NOP ((void)0)

__global__ __launch_bounds__(512, 2)
void gemm8(const u16* __restrict__ xb, const u16* __restrict__ Wb,
           const float* __restrict__ bias, float* __restrict__ out) {
  __shared__ u16 lds[65536];   // 128 KiB: A[2buf][2half][128][64] | B same

  const int bid = blockIdx.x;                  // 256 blocks
  const int swz = (bid & 7) * 32 + (bid >> 3); // XCD-aware, bijective (256%8==0)
  const int tm = swz >> 2, tn = swz & 3;
  const int m0 = tm * 256, n0 = tn * 256;

  const int t = threadIdx.x, w = t >> 6, l = t & 63;
  const int wr = w >> 2, wcn = w & 3;

  f32x4 acc[2][4][2][2];
  #pragma unroll
  for (int a = 0; a < 2; ++a)
    #pragma unroll
    for (int b2 = 0; b2 < 4; ++b2)
      #pragma unroll
      for (int c2 = 0; c2 < 2; ++c2)
        #pragma unroll
        for (int d2 = 0; d2 < 2; ++d2)
          acc[a][b2][c2][d2] = (f32x4){0.f, 0.f, 0.f, 0.f};

  // prologue: tile0 (all 4 halves) + tile1 (A0,B0); force tile0 landed
  STAGE_A(0,0,0); STAGE_B(0,0,0); STAGE_A(0,1,0); STAGE_B(0,1,0);
  STAGE_A(1,0,1); STAGE_B(1,0,1);
  VM4;
  __builtin_amdgcn_s_barrier();

  for (int it = 0; it < 15; ++it) {
    const int t1k = 2*it + 1, t2k = 2*it + 2, t3k = 2*it + 3;
    PHASE(0,0,0, STAGE_A(1,1,t1k), NOP);
    PHASE(0,0,1, STAGE_B(1,1,t1k), NOP);
    PHASE(0,1,0, STAGE_A(0,0,t2k), NOP);
    PHASE(0,1,1, STAGE_B(0,0,t2k), VM4);
    PHASE(1,0,0, STAGE_A(0,1,t2k), NOP);
    PHASE(1,0,1, STAGE_B(0,1,t2k), NOP);
    PHASE(1,1,0, STAGE_A(1,0,t3k), NOP);
    PHASE(1,1,1, STAGE_B(1,0,t3k), VM4);
  }
  // peeled last iter (tiles 30,31): only stage tile31's A1/B1; drain at p4
  PHASE(0,0,0, STAGE_A(1,1,31), NOP);
  PHASE(0,0,1, STAGE_B(1,1,31), NOP);
  PHASE(0,1,0, NOP, NOP);
  PHASE(0,1,1, NOP, VM0);
  PHASE(1,0,0, NOP, NOP);
  PHASE(1,0,1, NOP, NOP);
  PHASE(1,1,0, NOP, NOP);
  PHASE(1,1,1, NOP, NOP);

  // epilogue: +bias, masked store
  #pragma unroll
  for (int mh = 0; mh < 2; ++mh)
    #pragma unroll
    for (int nh = 0; nh < 2; ++nh)
      #pragma unroll
      for (int fc = 0; fc < 2; ++fc) {
        int col = n0 + nh*128 + wcn*32 + fc*16 + (l & 15);
        if (col < C_COLS) {
          float bv = bias[col];
          #pragma unroll
          for (int fr = 0; fr < 4; ++fr) {
            int row0 = m0 + mh*128 + wr*64 + fr*16 + ((l >> 4) << 2);
            #pragma unroll
            for (int j = 0; j < 4; ++j)
              out[(size_t)(row0 + j) * C_COLS + col] = acc[mh][fr][nh][fc][j] + bv;
          }
        }
      }
}

// ---------------------------------------------------------------------------
// Fallback (small ws): R1 kernels
// ---------------------------------------------------------------------------
__global__ __launch_bounds__(256)
void prep_w_fb(const float* __restrict__ W, u16* __restrict__ Wb,
               float* __restrict__ norms) {
  const int r = blockIdx.x;
  const int t = threadIdx.x;
  const float* row = W + (size_t)r * D_DIM;
  const int c = t * 8;
  float4 v0 = *reinterpret_cast<const float4*>(row + c);
  float4 v1 = *reinterpret_cast<const float4*>(row + c + 4);
  float ss = v0.x*v0.x + v0.y*v0.y + v0.z*v0.z + v0.w*v0.w
           + v1.x*v1.x + v1.y*v1.y + v1.z*v1.z + v1.w*v1.w;
  uint32_t p0 = (uint32_t)f2bf(v0.x) | ((uint32_t)f2bf(v0.y) << 16);
  uint32_t p1 = (uint32_t)f2bf(v0.z) | ((uint32_t)f2bf(v0.w) << 16);
  uint32_t p2 = (uint32_t)f2bf(v1.x) | ((uint32_t)f2bf(v1.y) << 16);
  uint32_t p3 = (uint32_t)f2bf(v1.z) | ((uint32_t)f2bf(v1.w) << 16);
  const int mask = (r & 7) << 3;
  uint4 val; val.x = p0; val.y = p1; val.z = p2; val.w = p3;
  *reinterpret_cast<uint4*>(Wb + (size_t)r * D_DIM + (c ^ mask)) = val;
  #pragma unroll
  for (int m = 32; m; m >>= 1) ss += __shfl_xor(ss, m);
  __shared__ float wss[4];
  if ((t & 63) == 0) wss[t >> 6] = ss;
  __syncthreads();
  if (t == 0) norms[r] = sqrtf(wss[0] + wss[1] + wss[2] + wss[3]);
}

__global__ __launch_bounds__(256)
void gemm_fb(const float* __restrict__ x, const u16* __restrict__ Wb,
             const float* __restrict__ bias, float* __restrict__ out) {
  __shared__ u16 lds[(128 + 128) * 64];
  const int bid = blockIdx.x;
  const int cpx = gridDim.x >> 3;
  const int swz = (bid & 7) * cpx + (bid >> 3);
  const int tn = swz & 7, tm = swz >> 3;
  const int m0 = tm * 128, n0 = tn * 128;
  const int t = threadIdx.x, w = t >> 6, l = t & 63;
  const int wr = w >> 1, wc = w & 1;
  f32x4 acc[4][4];
  #pragma unroll
  for (int i = 0; i < 4; ++i)
    #pragma unroll
    for (int j = 0; j < 4; ++j) acc[i][j] = (f32x4){0.f,0.f,0.f,0.f};
  const int ar = w * 32 + (l >> 4);
  const int ac4 = (l & 15) * 4;
  const float* aptr = x + (size_t)(m0 + ar) * D_DIM + ac4;
  for (int k0 = 0; k0 < D_DIM; k0 += 64) {
    #pragma unroll
    for (int i = 0; i < 4; ++i) {
      int ci = w * 4 + i;
      int br = ci * 8 + (l >> 3);
      int wrow = n0 + br; if (wrow >= C_COLS) wrow = C_COLS - 1;
      const char* src = (const char*)Wb + (size_t)wrow * (D_DIM * 2)
                        + k0 * 2 + (l & 7) * 16;
      u16* dst = lds + 128*64 + ci * 512;
      __builtin_amdgcn_global_load_lds(
          (const __attribute__((address_space(1))) void*)src,
          (__attribute__((address_space(3))) void*)dst, 16, 0, 0);
    }
    #pragma unroll
    for (int i = 0; i < 8; ++i) {
      int r = ar + i * 4;
      float4 v = *reinterpret_cast<const float4*>(aptr + (size_t)(i*4)*D_DIM + k0);
      ushort4 h;
      h.x = f2bf(v.x); h.y = f2bf(v.y); h.z = f2bf(v.z); h.w = f2bf(v.w);
      *reinterpret_cast<ushort4*>(&lds[r * 64 + (ac4 ^ ((r & 7) << 3))]) = h;
    }
    __syncthreads();
    #pragma unroll
    for (int kk = 0; kk < 64; kk += 32) {
      const int kg = kk + ((l >> 4) << 3);
      bf16x8 af[4], bfr[4];
      #pragma unroll
      for (int mi = 0; mi < 4; ++mi) {
        int row = wr * 64 + mi * 16 + (l & 15);
        af[mi] = *reinterpret_cast<const bf16x8*>(&lds[row*64 + (kg ^ ((row&7)<<3))]);
      }
      #pragma unroll
      for (int ni = 0; ni < 4; ++ni) {
        int row = wc * 64 + ni * 16 + (l & 15);
        bfr[ni] = *reinterpret_cast<const bf16x8*>(&lds[128*64 + row*64 + (kg ^ ((row&7)<<3))]);
      }
      #pragma unroll
      for (int mi = 0; mi < 4; ++mi)
        #pragma unroll
        for (int ni = 0; ni < 4; ++ni)
          acc[mi][ni] = __builtin_amdgcn_mfma_f32_16x16x32_bf16(
              af[mi], bfr[ni], acc[mi][ni], 0, 0, 0);
    }
    __syncthreads();
  }
  #pragma unroll
  for (int ni = 0; ni < 4; ++ni) {
    int col = n0 + wc * 64 + ni * 16 + (l & 15);
    if (col < C_COLS) {
      float bv = bias[col];
      #pragma unroll
      for (int mi = 0; mi < 4; ++mi) {
        int row0 = m0 + wr * 64 + mi * 16 + ((l >> 4) << 2);
        #pragma unroll
        for (int j = 0; j < 4; ++j)
          out[(size_t)(row0 + j) * C_COLS + col] = acc[mi][ni][j] + bv;
      }
    }
  }
}

// ---------------------------------------------------------------------------
// selector: per-row top2 / norm-top2 / softmax stats -> tanh ensemble
// ---------------------------------------------------------------------------
__global__ __launch_bounds__(256)
void selector(const float* __restrict__ logits, const float* __restrict__ norms,
              const float* __restrict__ selw, const float* __restrict__ selt,
              const float* __restrict__ ethr, float* __restrict__ out) {
  __shared__ float nrm[C_COLS];
  const int t = threadIdx.x;
  for (int i = t; i < C_COLS; i += 256) nrm[i] = norms[i];
  __syncthreads();

  const int w = t >> 6, l = t & 63;
  const int row = blockIdx.x * 4 + w;
  const float* lp = logits + (size_t)row * C_COLS;

  float lg[16];
  float t1 = -3.4e38f, t2 = -3.4e38f, n1 = -3.4e38f, n2 = -3.4e38f;
  #pragma unroll
  for (int i = 0; i < 16; ++i) {
    int idx = l + i * 64;
    float v = (idx < C_COLS) ? lp[idx] : -3.4e38f;
    lg[i] = v;
    if (v > t1) { t2 = t1; t1 = v; } else if (v > t2) t2 = v;
    float nv = (idx < C_COLS) ? v / (nrm[idx] + 1e-8f) : -3.4e38f;
    if (nv > n1) { n2 = n1; n1 = nv; } else if (nv > n2) n2 = nv;
  }
  #pragma unroll
  for (int m = 1; m < 64; m <<= 1) {
    float o1 = __shfl_xor(t1, m), o2 = __shfl_xor(t2, m);
    if (o1 > t1) { t2 = fmaxf(t1, o2); t1 = o1; } else t2 = fmaxf(t2, o1);
    float p1 = __shfl_xor(n1, m), p2 = __shfl_xor(n2, m);
    if (p1 > n1) { n2 = fmaxf(n1, p2); n1 = p1; } else n2 = fmaxf(n2, p1);
  }
  const float mx = t1;

  float S = 0.f, sq = 0.f;
  float ex[16];
  #pragma unroll
  for (int i = 0; i < 16; ++i) {
    int idx = l + i * 64;
    float e = (idx < C_COLS) ? __expf(lg[i] - mx) : 0.f;
    ex[i] = e; S += e; sq += e * e;
  }
  #pragma unroll
  for (int m = 1; m < 64; m <<= 1) { S += __shfl_xor(S, m); sq += __shfl_xor(sq, m); }

  float ent = 0.f;
  #pragma unroll
  for (int i = 0; i < 16; ++i) {
    int idx = l + i * 64;
    if (idx < C_COLS) {
      float p = ex[i] / S;
      ent += p * __logf(p + 1e-10f);
    }
  }
  #pragma unroll
  for (int m = 1; m < 64; m <<= 1) ent += __shfl_xor(ent, m);

  if (l == 0) {
    float sc0 = 1.f / S;
    float sc1 = 1.f - (S * S) / sq;
    float sc2 = ent;
    float sc3 = n1 - n2;
    float sc4 = t1 - t2;
    float ens = selw[0] * tanhf(sc0 - selt[0])
              + selw[1] * tanhf(sc1 - selt[1])
              + selw[2] * tanhf(sc2 - selt[2])
              + selw[3] * tanhf(sc3 - selt[3])
              + selw[4] * tanhf(sc4 - selt[4]);
    out[row] = tanhf(ens - ethr[0]);
  }
}

// ---------------------------------------------------------------------------
extern "C" void kernel_launch(void* const* d_in, const int* in_sizes, int n_in,
                              void* d_out, int out_size, void* d_ws, size_t ws_size,
                              hipStream_t stream) {
  const float* x    = (const float*)d_in[0];
  const float* W    = (const float*)d_in[1];
  const float* b    = (const float*)d_in[2];
  const float* selw = (const float*)d_in[3];
  const float* selt = (const float*)d_in[4];
  const float* ethr = (const float*)d_in[5];
  float* out = (float*)d_out;

  u16*   Wb    = (u16*)d_ws;                                  // 4,096,000 B
  float* norms = (float*)((char*)d_ws + 4096000);             // 4,000 B
  u16*   xb    = (u16*)((char*)d_ws + 4100096);               // 67,108,864 B
  const size_t need = 4100096 + (size_t)B_ROWS * D_DIM * 2;

  if (ws_size >= need) {
    prep<<<C_COLS + B_ROWS, 256, 0, stream>>>(W, x, Wb, xb, norms);
    gemm8<<<256, 512, 0, stream>>>(xb, Wb, b, out);
  } else {
    prep_w_fb<<<C_COLS, 256, 0, stream>>>(W, Wb, norms);
    gemm_fb<<<(B_ROWS / 128) * 8, 256, 0, stream>>>(x, Wb, b, out);
  }
  selector<<<B_ROWS / 4, 256, 0, stream>>>(out, norms, selw, selt, ethr,
                                           out + (size_t)B_ROWS * C_COLS);
}

// Round 4
// 133.390 us; speedup vs baseline: 1.1837x; 1.0671x over previous
//
#include <hip/hip_runtime.h>
#include <stdint.h>

#define B_ROWS 16384
#define C_COLS 1000
#define D_DIM  2048

typedef __bf16 bf16x8 __attribute__((ext_vector_type(8)));
typedef float  f32x4  __attribute__((ext_vector_type(4)));
typedef unsigned short u16;

__device__ __forceinline__ u16 f2bf(float f) {
  union { float f; uint32_t u; } v; v.f = f;
  return (u16)((v.u + 0x7FFFu + ((v.u >> 16) & 1u)) >> 16);
}

// ---------------------------------------------------------------------------
// prep: blocks 0..999 cast W row -> Wb (swizzled) + norms; blocks 1000..17383
// cast x row (r-1000) -> xb (swizzled). Swizzle: elem c -> c ^ ((row&7)<<3).
// ---------------------------------------------------------------------------
__global__ __launch_bounds__(256)
void prep(const float* __restrict__ W, const float* __restrict__ x,
          u16* __restrict__ Wb, u16* __restrict__ xb, float* __restrict__ norms) {
  const int r = blockIdx.x;
  const int t = threadIdx.x;
  const bool isW = (r < C_COLS);
  const float* src = isW ? (W + (size_t)r * D_DIM)
                         : (x + (size_t)(r - C_COLS) * D_DIM);
  u16* dst = isW ? (Wb + (size_t)r * D_DIM)
                 : (xb + (size_t)(r - C_COLS) * D_DIM);
  const int c = t * 8;
  float4 v0 = *reinterpret_cast<const float4*>(src + c);
  float4 v1 = *reinterpret_cast<const float4*>(src + c + 4);
  uint32_t p0 = (uint32_t)f2bf(v0.x) | ((uint32_t)f2bf(v0.y) << 16);
  uint32_t p1 = (uint32_t)f2bf(v0.z) | ((uint32_t)f2bf(v0.w) << 16);
  uint32_t p2 = (uint32_t)f2bf(v1.x) | ((uint32_t)f2bf(v1.y) << 16);
  uint32_t p3 = (uint32_t)f2bf(v1.z) | ((uint32_t)f2bf(v1.w) << 16);
  const int row_id = isW ? r : (r - C_COLS);
  const int m2 = (row_id & 7) << 3;
  uint4 val; val.x = p0; val.y = p1; val.z = p2; val.w = p3;
  *reinterpret_cast<uint4*>(dst + (c ^ m2)) = val;
  if (isW) {
    float ss = v0.x*v0.x + v0.y*v0.y + v0.z*v0.z + v0.w*v0.w
             + v1.x*v1.x + v1.y*v1.y + v1.z*v1.z + v1.w*v1.w;
    #pragma unroll
    for (int m = 32; m; m >>= 1) ss += __shfl_xor(ss, m);
    __shared__ float wss[4];
    if ((t & 63) == 0) wss[t >> 6] = ss;
    __syncthreads();
    if (t == 0) norms[r] = sqrtf(wss[0] + wss[1] + wss[2] + wss[3]);
  }
}

// ---------------------------------------------------------------------------
// gemm8: 256x256 tile, BK=64, 8 waves, 8-phase schedule with FRAGMENT REUSE
// (24 ds_read_b128 per K-tile per wave instead of 48), counted vmcnt,
// XOR-swizzled LDS, gload_lds both operands.
// ---------------------------------------------------------------------------
#define ABASE(B,H) (((B)*2+(H))*8192)
#define BBASE(B,H) (32768 + ((B)*2+(H))*8192)

#define STAGE_A(BUF,H,KT) { _Pragma("unroll") for (int j_=0;j_<2;++j_){ \
    const char* s_ = (const char*)xb + \
      (((size_t)(m0+(H)*128+j_*64+w*8+(l>>3)))*D_DIM + (KT)*64 + (l&7)*8)*2; \
    u16* d_ = lds + ABASE(BUF,H) + (j_*64 + w*8)*64; \
    __builtin_amdgcn_global_load_lds( \
      (const __attribute__((address_space(1))) void*)s_, \
      (__attribute__((address_space(3))) void*)d_, 16, 0, 0); } }

#define STAGE_B(BUF,H,KT) { _Pragma("unroll") for (int j_=0;j_<2;++j_){ \
    int gr_ = n0+(H)*128+j_*64+w*8+(l>>3); if (gr_ >= C_COLS) gr_ = C_COLS-1; \
    const char* s_ = (const char*)Wb + \
      (((size_t)gr_)*D_DIM + (KT)*64 + (l&7)*8)*2; \
    u16* d_ = lds + BBASE(BUF,H) + (j_*64 + w*8)*64; \
    __builtin_amdgcn_global_load_lds( \
      (const __attribute__((address_space(1))) void*)s_, \
      (__attribute__((address_space(3))) void*)d_, 16, 0, 0); } }

#define READ_A(BUF,MH) { _Pragma("unroll") for (int ks_=0;ks_<2;++ks_) \
  _Pragma("unroll") for (int fr_=0;fr_<4;++fr_){ \
    int ra_ = wr*64 + fr_*16 + (l&15); \
    int ca_ = (ks_*32 + ((l>>4)<<3)) ^ ((ra_&7)<<3); \
    Acur[ks_][fr_] = *reinterpret_cast<const bf16x8*>( \
        &lds[ABASE(BUF,MH) + ra_*64 + ca_]); } }

#define READ_B(BUF,NH,DST) { _Pragma("unroll") for (int ks_=0;ks_<2;++ks_) \
  _Pragma("unroll") for (int fc_=0;fc_<2;++fc_){ \
    int rb_ = wcn*32 + fc_*16 + (l&15); \
    int cb_ = (ks_*32 + ((l>>4)<<3)) ^ ((rb_&7)<<3); \
    DST[ks_][fc_] = *reinterpret_cast<const bf16x8*>( \
        &lds[BBASE(BUF,NH) + rb_*64 + cb_]); } }

#define MMA(MH,NH,BSRC) { \
  __builtin_amdgcn_s_setprio(1); \
  _Pragma("unroll") for (int ks_=0;ks_<2;++ks_) \
    _Pragma("unroll") for (int fr_=0;fr_<4;++fr_) \
      _Pragma("unroll") for (int fc_=0;fc_<2;++fc_) \
        acc[MH][fr_][NH][fc_] = __builtin_amdgcn_mfma_f32_16x16x32_bf16( \
            Acur[ks_][fr_], BSRC[ks_][fc_], acc[MH][fr_][NH][fc_], 0, 0, 0); \
  __builtin_amdgcn_s_setprio(0); }

#define BAR  __builtin_amdgcn_s_barrier()
#define LG0  asm volatile("s_waitcnt lgkmcnt(0)" ::: "memory")
#define LG8  asm volatile("s_waitcnt lgkmcnt(8)" ::: "memory")
#define SCHB __builtin_amdgcn_sched_barrier(0)
#define VM4  asm volatile("s_waitcnt vmcnt(4)" ::: "memory")
#define VM0  asm volatile("s_waitcnt vmcnt(0)" ::: "memory")

__global__ __launch_bounds__(512, 2)
void gemm8(const u16* __restrict__ xb, const u16* __restrict__ Wb,
           const float* __restrict__ bias, float* __restrict__ out) {
  __shared__ u16 lds[65536];   // 128 KiB: A[2buf][2half][128][64] | B same

  const int bid = blockIdx.x;                  // 256 blocks
  const int swz = (bid & 7) * 32 + (bid >> 3); // XCD-aware, bijective
  const int tm = swz >> 2, tn = swz & 3;
  const int m0 = tm * 256, n0 = tn * 256;

  const int t = threadIdx.x, w = t >> 6, l = t & 63;
  const int wr = w >> 2, wcn = w & 3;

  f32x4 acc[2][4][2][2];
  #pragma unroll
  for (int a = 0; a < 2; ++a)
    #pragma unroll
    for (int b2 = 0; b2 < 4; ++b2)
      #pragma unroll
      for (int c2 = 0; c2 < 2; ++c2)
        #pragma unroll
        for (int d2 = 0; d2 < 2; ++d2)
          acc[a][b2][c2][d2] = (f32x4){0.f, 0.f, 0.f, 0.f};

  bf16x8 Acur[2][4], B0c[2][2], B1c[2][2];

  // prologue: tile0 (all 4 halves, buf0) + tile1 (A0,B0, buf1)
  STAGE_A(0,0,0); STAGE_B(0,0,0); STAGE_A(0,1,0); STAGE_B(0,1,0);
  STAGE_A(1,0,1); STAGE_B(1,0,1);
  VM4;
  BAR;

  for (int it = 0; it < 15; ++it) {
    const int t1k = 2*it + 1, t2k = 2*it + 2, t3k = 2*it + 3;
    // P1: A0 x B0 (read both, cache B0)
    READ_A(0,0); READ_B(0,0,B0c); STAGE_A(1,1,t1k); LG8;
    BAR; LG0; SCHB; MMA(0,0,B0c); BAR;
    // P2: A0 x B1 (read B1 only)
    READ_B(0,1,B1c); STAGE_B(1,1,t1k);
    BAR; LG0; SCHB; MMA(0,1,B1c); BAR;
    // P3: A1 x B1 (read A1 only)
    READ_A(0,1); STAGE_A(0,0,t2k);
    BAR; LG0; SCHB; MMA(1,1,B1c); BAR;
    // P4: A1 x B0 (no reads)
    STAGE_B(0,0,t2k);
    BAR; SCHB; MMA(1,0,B0c); VM4; BAR;
    // P5-P8: same on buf1
    READ_A(1,0); READ_B(1,0,B0c); STAGE_A(0,1,t2k); LG8;
    BAR; LG0; SCHB; MMA(0,0,B0c); BAR;
    READ_B(1,1,B1c); STAGE_B(0,1,t2k);
    BAR; LG0; SCHB; MMA(0,1,B1c); BAR;
    READ_A(1,1); STAGE_A(1,0,t3k);
    BAR; LG0; SCHB; MMA(1,1,B1c); BAR;
    STAGE_B(1,0,t3k);
    BAR; SCHB; MMA(1,0,B0c); VM4; BAR;
  }
  // peeled last iter (tiles 30 buf0, 31 buf1)
  READ_A(0,0); READ_B(0,0,B0c); STAGE_A(1,1,31); LG8;
  BAR; LG0; SCHB; MMA(0,0,B0c); BAR;
  READ_B(0,1,B1c); STAGE_B(1,1,31);
  BAR; LG0; SCHB; MMA(0,1,B1c); BAR;
  READ_A(0,1);
  BAR; LG0; SCHB; MMA(1,1,B1c); BAR;
  BAR; SCHB; MMA(1,0,B0c); VM0; BAR;
  READ_A(1,0); READ_B(1,0,B0c); LG8;
  BAR; LG0; SCHB; MMA(0,0,B0c); BAR;
  READ_B(1,1,B1c);
  BAR; LG0; SCHB; MMA(0,1,B1c); BAR;
  READ_A(1,1);
  BAR; LG0; SCHB; MMA(1,1,B1c); BAR;
  SCHB; MMA(1,0,B0c);

  // epilogue: +bias, masked store
  #pragma unroll
  for (int mh = 0; mh < 2; ++mh)
    #pragma unroll
    for (int nh = 0; nh < 2; ++nh)
      #pragma unroll
      for (int fc = 0; fc < 2; ++fc) {
        int col = n0 + nh*128 + wcn*32 + fc*16 + (l & 15);
        if (col < C_COLS) {
          float bv = bias[col];
          #pragma unroll
          for (int fr = 0; fr < 4; ++fr) {
            int row0 = m0 + mh*128 + wr*64 + fr*16 + ((l >> 4) << 2);
            #pragma unroll
            for (int j = 0; j < 4; ++j)
              out[(size_t)(row0 + j) * C_COLS + col] = acc[mh][fr][nh][fc][j] + bv;
          }
        }
      }
}

// ---------------------------------------------------------------------------
// Fallback (small ws): R1 kernels
// ---------------------------------------------------------------------------
__global__ __launch_bounds__(256)
void prep_w_fb(const float* __restrict__ W, u16* __restrict__ Wb,
               float* __restrict__ norms) {
  const int r = blockIdx.x;
  const int t = threadIdx.x;
  const float* row = W + (size_t)r * D_DIM;
  const int c = t * 8;
  float4 v0 = *reinterpret_cast<const float4*>(row + c);
  float4 v1 = *reinterpret_cast<const float4*>(row + c + 4);
  float ss = v0.x*v0.x + v0.y*v0.y + v0.z*v0.z + v0.w*v0.w
           + v1.x*v1.x + v1.y*v1.y + v1.z*v1.z + v1.w*v1.w;
  uint32_t p0 = (uint32_t)f2bf(v0.x) | ((uint32_t)f2bf(v0.y) << 16);
  uint32_t p1 = (uint32_t)f2bf(v0.z) | ((uint32_t)f2bf(v0.w) << 16);
  uint32_t p2 = (uint32_t)f2bf(v1.x) | ((uint32_t)f2bf(v1.y) << 16);
  uint32_t p3 = (uint32_t)f2bf(v1.z) | ((uint32_t)f2bf(v1.w) << 16);
  const int mask = (r & 7) << 3;
  uint4 val; val.x = p0; val.y = p1; val.z = p2; val.w = p3;
  *reinterpret_cast<uint4*>(Wb + (size_t)r * D_DIM + (c ^ mask)) = val;
  #pragma unroll
  for (int m = 32; m; m >>= 1) ss += __shfl_xor(ss, m);
  __shared__ float wss[4];
  if ((t & 63) == 0) wss[t >> 6] = ss;
  __syncthreads();
  if (t == 0) norms[r] = sqrtf(wss[0] + wss[1] + wss[2] + wss[3]);
}

__global__ __launch_bounds__(256)
void gemm_fb(const float* __restrict__ x, const u16* __restrict__ Wb,
             const float* __restrict__ bias, float* __restrict__ out) {
  __shared__ u16 lds[(128 + 128) * 64];
  const int bid = blockIdx.x;
  const int cpx = gridDim.x >> 3;
  const int swz = (bid & 7) * cpx + (bid >> 3);
  const int tn = swz & 7, tm = swz >> 3;
  const int m0 = tm * 128, n0 = tn * 128;
  const int t = threadIdx.x, w = t >> 6, l = t & 63;
  const int wr = w >> 1, wc = w & 1;
  f32x4 acc[4][4];
  #pragma unroll
  for (int i = 0; i < 4; ++i)
    #pragma unroll
    for (int j = 0; j < 4; ++j) acc[i][j] = (f32x4){0.f,0.f,0.f,0.f};
  const int ar = w * 32 + (l >> 4);
  const int ac4 = (l & 15) * 4;
  const float* aptr = x + (size_t)(m0 + ar) * D_DIM + ac4;
  for (int k0 = 0; k0 < D_DIM; k0 += 64) {
    #pragma unroll
    for (int i = 0; i < 4; ++i) {
      int ci = w * 4 + i;
      int br = ci * 8 + (l >> 3);
      int wrow = n0 + br; if (wrow >= C_COLS) wrow = C_COLS - 1;
      const char* src = (const char*)Wb + (size_t)wrow * (D_DIM * 2)
                        + k0 * 2 + (l & 7) * 16;
      u16* dst = lds + 128*64 + ci * 512;
      __builtin_amdgcn_global_load_lds(
          (const __attribute__((address_space(1))) void*)src,
          (__attribute__((address_space(3))) void*)dst, 16, 0, 0);
    }
    #pragma unroll
    for (int i = 0; i < 8; ++i) {
      int r = ar + i * 4;
      float4 v = *reinterpret_cast<const float4*>(aptr + (size_t)(i*4)*D_DIM + k0);
      ushort4 h;
      h.x = f2bf(v.x); h.y = f2bf(v.y); h.z = f2bf(v.z); h.w = f2bf(v.w);
      *reinterpret_cast<ushort4*>(&lds[r * 64 + (ac4 ^ ((r & 7) << 3))]) = h;
    }
    __syncthreads();
    #pragma unroll
    for (int kk = 0; kk < 64; kk += 32) {
      const int kg = kk + ((l >> 4) << 3);
      bf16x8 af[4], bfr[4];
      #pragma unroll
      for (int mi = 0; mi < 4; ++mi) {
        int row = wr * 64 + mi * 16 + (l & 15);
        af[mi] = *reinterpret_cast<const bf16x8*>(&lds[row*64 + (kg ^ ((row&7)<<3))]);
      }
      #pragma unroll
      for (int ni = 0; ni < 4; ++ni) {
        int row = wc * 64 + ni * 16 + (l & 15);
        bfr[ni] = *reinterpret_cast<const bf16x8*>(&lds[128*64 + row*64 + (kg ^ ((row&7)<<3))]);
      }
      #pragma unroll
      for (int mi = 0; mi < 4; ++mi)
        #pragma unroll
        for (int ni = 0; ni < 4; ++ni)
          acc[mi][ni] = __builtin_amdgcn_mfma_f32_16x16x32_bf16(
              af[mi], bfr[ni], acc[mi][ni], 0, 0, 0);
    }
    __syncthreads();
  }
  #pragma unroll
  for (int ni = 0; ni < 4; ++ni) {
    int col = n0 + wc * 64 + ni * 16 + (l & 15);
    if (col < C_COLS) {
      float bv = bias[col];
      #pragma unroll
      for (int mi = 0; mi < 4; ++mi) {
        int row0 = m0 + wr * 64 + mi * 16 + ((l >> 4) << 2);
        #pragma unroll
        for (int j = 0; j < 4; ++j)
          out[(size_t)(row0 + j) * C_COLS + col] = acc[mi][ni][j] + bv;
      }
    }
  }
}

// ---------------------------------------------------------------------------
// selector: per-row top2 / norm-top2 / softmax stats -> tanh ensemble
// float4-vectorized loads (tail-masked; reads stay within d_out)
// ---------------------------------------------------------------------------
__global__ __launch_bounds__(256)
void selector(const float* __restrict__ logits, const float* __restrict__ norms,
              const float* __restrict__ selw, const float* __restrict__ selt,
              const float* __restrict__ ethr, float* __restrict__ out) {
  __shared__ float nrm[1024];
  const int t = threadIdx.x;
  #pragma unroll
  for (int i = 0; i < 4; ++i) {
    int idx = t + i * 256;
    nrm[idx] = (idx < C_COLS) ? norms[idx] : 1.0f;
  }
  __syncthreads();

  const int w = t >> 6, l = t & 63;
  const int row = blockIdx.x * 4 + w;
  const float* lp = logits + (size_t)row * C_COLS;

  float lg[16];
  float t1 = -3.4e38f, t2 = -3.4e38f, n1 = -3.4e38f, n2 = -3.4e38f;
  #pragma unroll
  for (int i = 0; i < 4; ++i) {
    float4 v4 = *reinterpret_cast<const float4*>(lp + l * 4 + i * 256);
    #pragma unroll
    for (int j = 0; j < 4; ++j) {
      int idx = l * 4 + i * 256 + j;
      float raw = (j == 0) ? v4.x : (j == 1) ? v4.y : (j == 2) ? v4.z : v4.w;
      bool ok = (idx < C_COLS);
      float v = ok ? raw : -3.4e38f;
      lg[i * 4 + j] = v;
      if (v > t1) { t2 = t1; t1 = v; } else if (v > t2) t2 = v;
      float nv = ok ? raw / (nrm[idx] + 1e-8f) : -3.4e38f;
      if (nv > n1) { n2 = n1; n1 = nv; } else if (nv > n2) n2 = nv;
    }
  }
  // wave-wide top-2 merge (raw + normalized)
  #pragma unroll
  for (int m = 1; m < 64; m <<= 1) {
    float o1 = __shfl_xor(t1, m), o2 = __shfl_xor(t2, m);
    if (o1 > t1) { t2 = fmaxf(t1, o2); t1 = o1; } else t2 = fmaxf(t2, o1);
    float p1 = __shfl_xor(n1, m), p2 = __shfl_xor(n2, m);
    if (p1 > n1) { n2 = fmaxf(n1, p2); n1 = p1; } else n2 = fmaxf(n2, p1);
  }
  const float mx = t1;

  float S = 0.f, sq = 0.f;
  float ex[16];
  #pragma unroll
  for (int i = 0; i < 16; ++i) {
    float e = (lg[i] > -1e38f) ? __expf(lg[i] - mx) : 0.f;
    ex[i] = e; S += e; sq += e * e;
  }
  #pragma unroll
  for (int m = 1; m < 64; m <<= 1) { S += __shfl_xor(S, m); sq += __shfl_xor(sq, m); }

  float ent = 0.f;
  #pragma unroll
  for (int i = 0; i < 16; ++i) {
    if (lg[i] > -1e38f) {
      float p = ex[i] / S;
      ent += p * __logf(p + 1e-10f);
    }
  }
  #pragma unroll
  for (int m = 1; m < 64; m <<= 1) ent += __shfl_xor(ent, m);

  if (l == 0) {
    float sc0 = 1.f / S;
    float sc1 = 1.f - (S * S) / sq;
    float sc2 = ent;
    float sc3 = n1 - n2;
    float sc4 = t1 - t2;
    float ens = selw[0] * tanhf(sc0 - selt[0])
              + selw[1] * tanhf(sc1 - selt[1])
              + selw[2] * tanhf(sc2 - selt[2])
              + selw[3] * tanhf(sc3 - selt[3])
              + selw[4] * tanhf(sc4 - selt[4]);
    out[row] = tanhf(ens - ethr[0]);
  }
}

// ---------------------------------------------------------------------------
extern "C" void kernel_launch(void* const* d_in, const int* in_sizes, int n_in,
                              void* d_out, int out_size, void* d_ws, size_t ws_size,
                              hipStream_t stream) {
  const float* x    = (const float*)d_in[0];
  const float* W    = (const float*)d_in[1];
  const float* b    = (const float*)d_in[2];
  const float* selw = (const float*)d_in[3];
  const float* selt = (const float*)d_in[4];
  const float* ethr = (const float*)d_in[5];
  float* out = (float*)d_out;

  u16*   Wb    = (u16*)d_ws;                                  // 4,096,000 B
  float* norms = (float*)((char*)d_ws + 4096000);             // 4,000 B
  u16*   xb    = (u16*)((char*)d_ws + 4100096);               // 67,108,864 B
  const size_t need = 4100096 + (size_t)B_ROWS * D_DIM * 2;

  if (ws_size >= need) {
    prep<<<C_COLS + B_ROWS, 256, 0, stream>>>(W, x, Wb, xb, norms);
    gemm8<<<256, 512, 0, stream>>>(xb, Wb, b, out);
  } else {
    prep_w_fb<<<C_COLS, 256, 0, stream>>>(W, Wb, norms);
    gemm_fb<<<(B_ROWS / 128) * 8, 256, 0, stream>>>(x, Wb, b, out);
  }
  selector<<<B_ROWS / 4, 256, 0, stream>>>(out, norms, selw, selt, ethr,
                                           out + (size_t)B_ROWS * C_COLS);
}